// Round 2
// baseline (438.540 us; speedup 1.0000x reference)
//
#include <hip/hip_runtime.h>

// Sparsemax along last axis of (4, 4096, 4096) fp32.
// ROW-PER-WAVE restructure: each 64-lane wave owns one full row in
// registers (16 float4 / lane). No LDS, no atomics, NO __syncthreads —
// every wave streams load -> max -> filter -> Newton -> store
// independently, so there are no block-wide vmcnt drains and no phases
// where 3/4 of the block idles (the previous structure's ~20% BW loss).
//
// tau solves sum(relu(x - tau)) = 1 via Newton from tau0 = max - 1
// (monotone non-decreasing, finite exact convergence). Only elements
// with x > max-1 can ever be active; each lane keeps its (<=4 w.h.p.)
// candidates in a 5-deep register shift-register. Slot 5 detects
// overflow (>=5 candidates in one lane) -> full register-scan Newton
// fallback (correctness path, never taken for Gaussian data).

constexpr int D = 4096;
constexpr int BLOCK = 256;            // 4 waves, 1 row per wave
constexpr int F4 = D / 64 / 4;        // 16 float4 per lane
constexpr int MAX_ITERS = 24;         // early-exit usually after ~6

__global__ __launch_bounds__(BLOCK) void sparsemax_kernel(
    const float* __restrict__ in, float* __restrict__ out, int nrows) {
  const int t = threadIdx.x;
  const int wave = t >> 6;
  const int lane = t & 63;
  const long long row = (long long)blockIdx.x * 4 + wave;
  if (row >= nrows) return;

  const float4* __restrict__ x4 =
      reinterpret_cast<const float4*>(in) + row * (long long)(D / 4);
  float4* __restrict__ y4 =
      reinterpret_cast<float4*>(out) + row * (long long)(D / 4);

  // ---- load row into registers (coalesced: lane + 64*c -> 1 KiB/instr) ----
  float4 v[F4];
#pragma unroll
  for (int c = 0; c < F4; c++) v[c] = x4[lane + 64 * c];

  // ---- wave max (lane-local tree + 6-step butterfly; all lanes get it) ----
  float m = -INFINITY;
#pragma unroll
  for (int c = 0; c < F4; c++)
    m = fmaxf(m, fmaxf(fmaxf(v[c].x, v[c].y), fmaxf(v[c].z, v[c].w)));
#pragma unroll
  for (int o = 32; o > 0; o >>= 1) m = fmaxf(m, __shfl_xor(m, o));

  const float thr = m - 1.0f;        // tau0; no x <= thr is ever active
  const float sentinel = thr - 1.0f; // never > tau (tau >= thr)

  // ---- lane-local candidate extraction (static shift-register, no LDS) ----
  // Chunk-max pregate: most chunks have no candidate -> exec-masked skip.
  float z0 = sentinel, z1 = sentinel, z2 = sentinel, z3 = sentinel;
  float z4 = sentinel;  // overflow detector: real value here <=> >=5 cands
#pragma unroll
  for (int c = 0; c < F4; c++) {
    const float4 q = v[c];
    const float cm = fmaxf(fmaxf(q.x, q.y), fmaxf(q.z, q.w));
    if (cm > thr) {
      if (q.x > thr) { z4 = z3; z3 = z2; z2 = z1; z1 = z0; z0 = q.x; }
      if (q.y > thr) { z4 = z3; z3 = z2; z2 = z1; z1 = z0; z0 = q.y; }
      if (q.z > thr) { z4 = z3; z3 = z2; z2 = z1; z1 = z0; z0 = q.z; }
      if (q.w > thr) { z4 = z3; z3 = z2; z2 = z1; z1 = z0; z0 = q.w; }
    }
  }

  float tau = thr;
  const int overflow = (z4 > sentinel) ? 1 : 0;
  if (!__any(overflow)) {
    // ---- hot path: <=4 candidates/lane, Newton with early exit ----
    for (int it = 0; it < MAX_ITERS; it++) {
      float S = 0.0f, K = 0.0f;
      if (z0 > tau) { S += z0; K += 1.0f; }
      if (z1 > tau) { S += z1; K += 1.0f; }
      if (z2 > tau) { S += z2; K += 1.0f; }
      if (z3 > tau) { S += z3; K += 1.0f; }
#pragma unroll
      for (int o = 32; o > 0; o >>= 1) {
        S += __shfl_xor(S, o);
        K += __shfl_xor(K, o);
      }
      const float nt = (S - 1.0f) / K;  // K >= 1: x_max = m > tau always
      if (nt == tau) break;             // wave-uniform (butterfly broadcast)
      tau = nt;
    }
  } else {
    // ---- fallback: scan all 64 registers per iter (correct for any input) ----
    for (int it = 0; it < MAX_ITERS; it++) {
      float S = 0.0f, K = 0.0f;
#pragma unroll
      for (int c = 0; c < F4; c++) {
        const float4 q = v[c];
        if (q.x > tau) { S += q.x; K += 1.0f; }
        if (q.y > tau) { S += q.y; K += 1.0f; }
        if (q.z > tau) { S += q.z; K += 1.0f; }
        if (q.w > tau) { S += q.w; K += 1.0f; }
      }
#pragma unroll
      for (int o = 32; o > 0; o >>= 1) {
        S += __shfl_xor(S, o);
        K += __shfl_xor(K, o);
      }
      const float nt = (S - 1.0f) / K;
      if (nt == tau) break;
      tau = nt;
    }
  }

  // ---- write p = max(x - tau, 0), coalesced float4 ----
#pragma unroll
  for (int c = 0; c < F4; c++) {
    float4 o;
    o.x = fmaxf(v[c].x - tau, 0.0f);
    o.y = fmaxf(v[c].y - tau, 0.0f);
    o.z = fmaxf(v[c].z - tau, 0.0f);
    o.w = fmaxf(v[c].w - tau, 0.0f);
    y4[lane + 64 * c] = o;
  }
}

extern "C" void kernel_launch(void* const* d_in, const int* in_sizes, int n_in,
                              void* d_out, int out_size, void* d_ws, size_t ws_size,
                              hipStream_t stream) {
  const float* in = (const float*)d_in[0];
  float* out = (float*)d_out;
  const int rows = in_sizes[0] / D;        // 16384
  const int blocks = (rows + 3) / 4;       // 1 row per wave, 4 waves/block
  sparsemax_kernel<<<blocks, BLOCK, 0, stream>>>(in, out, rows);
}

// Round 3
// 415.024 us; speedup vs baseline: 1.0567x; 1.0567x over previous
//
#include <hip/hip_runtime.h>

// Sparsemax along last axis of (4, 4096, 4096) fp32.
// WRITE-STREAM SPLIT: output is ~99.7% zeros (Gaussian rows keep ~14
// active elements of 4096). kernel_launch first zeroes the output with
// hipMemsetAsync (pure-write fill measured at 6.5 TB/s on this harness),
// then the kernel is READ-ONLY + tiny scatter: it never does the dense
// 256 MiB store that previously serialized behind tau. This removes the
// load-all -> compute-bubble -> store-all macro-phase structure that
// held both prior kernels at ~5.0 TB/s (80% of copy ceiling).
//
// Row-per-wave, row in registers, no LDS, no barriers. tau solves
// sum(relu(x - tau)) = 1 via Newton from tau0 = max - 1 (monotone,
// finite convergence; tau >= max-1 always). Candidates (x > max-1,
// ~14/row) are kept lane-locally in a 5-deep (value,index) register
// shift-register; overflow (>=5 in one lane) falls back to a full
// register-scan Newton + scatter (correct for any input, e.g. constant
// rows; never taken for Gaussian data).

constexpr int D = 4096;
constexpr int BLOCK = 256;            // 4 waves, 1 row per wave
constexpr int F4 = D / 64 / 4;        // 16 float4 per lane
constexpr int MAX_ITERS = 24;         // early-exit usually after ~6

__global__ __launch_bounds__(BLOCK) void sparsemax_kernel(
    const float* __restrict__ in, float* __restrict__ out, int nrows) {
  const int t = threadIdx.x;
  const int wave = t >> 6;
  const int lane = t & 63;
  const long long row = (long long)blockIdx.x * 4 + wave;
  if (row >= nrows) return;

  const float4* __restrict__ x4 =
      reinterpret_cast<const float4*>(in) + row * (long long)(D / 4);
  float* __restrict__ yrow = out + row * (long long)D;

  // ---- load row into registers (coalesced: lane + 64*c -> 1 KiB/instr) ----
  float4 v[F4];
#pragma unroll
  for (int c = 0; c < F4; c++) v[c] = x4[lane + 64 * c];

  // ---- wave max (lane-local tree + 6-step butterfly; all lanes get it) ----
  float m = -INFINITY;
#pragma unroll
  for (int c = 0; c < F4; c++)
    m = fmaxf(m, fmaxf(fmaxf(v[c].x, v[c].y), fmaxf(v[c].z, v[c].w)));
#pragma unroll
  for (int o = 32; o > 0; o >>= 1) m = fmaxf(m, __shfl_xor(m, o));

  const float thr = m - 1.0f;        // tau0; no x <= thr is ever active
  const float sentinel = thr - 1.0f; // never > tau (tau >= thr)

  // ---- lane-local (value,index) extraction, static shift-register ----
  float z0 = sentinel, z1 = sentinel, z2 = sentinel, z3 = sentinel;
  float z4 = sentinel;  // overflow detector: real value here <=> >=5 cands
  int i0 = 0, i1 = 0, i2 = 0, i3 = 0;
#pragma unroll
  for (int c = 0; c < F4; c++) {
    const float4 q = v[c];
    const float cm = fmaxf(fmaxf(q.x, q.y), fmaxf(q.z, q.w));
    if (cm > thr) {
      const int base = (lane + 64 * c) * 4;  // element index of q.x in row
      if (q.x > thr) { z4=z3; z3=z2; z2=z1; z1=z0; z0=q.x; i3=i2; i2=i1; i1=i0; i0=base+0; }
      if (q.y > thr) { z4=z3; z3=z2; z2=z1; z1=z0; z0=q.y; i3=i2; i2=i1; i1=i0; i0=base+1; }
      if (q.z > thr) { z4=z3; z3=z2; z2=z1; z1=z0; z0=q.z; i3=i2; i2=i1; i1=i0; i0=base+2; }
      if (q.w > thr) { z4=z3; z3=z2; z2=z1; z1=z0; z0=q.w; i3=i2; i2=i1; i1=i0; i0=base+3; }
    }
  }

  float tau = thr;
  const int overflow = (z4 > sentinel) ? 1 : 0;
  if (!__any(overflow)) {
    // ---- hot path: <=4 candidates/lane, Newton with early exit ----
    for (int it = 0; it < MAX_ITERS; it++) {
      float S = 0.0f, K = 0.0f;
      if (z0 > tau) { S += z0; K += 1.0f; }
      if (z1 > tau) { S += z1; K += 1.0f; }
      if (z2 > tau) { S += z2; K += 1.0f; }
      if (z3 > tau) { S += z3; K += 1.0f; }
#pragma unroll
      for (int o = 32; o > 0; o >>= 1) {
        S += __shfl_xor(S, o);
        K += __shfl_xor(K, o);
      }
      const float nt = (S - 1.0f) / K;  // K >= 1: x_max = m > tau always
      if (nt == tau) break;             // wave-uniform (butterfly broadcast)
      tau = nt;
    }
    // ---- scatter the <=4 actives/lane; zeros already written by memset ----
    if (z0 > tau) yrow[i0] = z0 - tau;
    if (z1 > tau) yrow[i1] = z1 - tau;
    if (z2 > tau) yrow[i2] = z2 - tau;
    if (z3 > tau) yrow[i3] = z3 - tau;
  } else {
    // ---- fallback: scan all 64 registers per iter (correct for any input) ----
    for (int it = 0; it < MAX_ITERS; it++) {
      float S = 0.0f, K = 0.0f;
#pragma unroll
      for (int c = 0; c < F4; c++) {
        const float4 q = v[c];
        if (q.x > tau) { S += q.x; K += 1.0f; }
        if (q.y > tau) { S += q.y; K += 1.0f; }
        if (q.z > tau) { S += q.z; K += 1.0f; }
        if (q.w > tau) { S += q.w; K += 1.0f; }
      }
#pragma unroll
      for (int o = 32; o > 0; o >>= 1) {
        S += __shfl_xor(S, o);
        K += __shfl_xor(K, o);
      }
      const float nt = (S - 1.0f) / K;
      if (nt == tau) break;
      tau = nt;
    }
    // scatter every active element (could be the whole row for degenerate input)
#pragma unroll
    for (int c = 0; c < F4; c++) {
      const float4 q = v[c];
      const int base = (lane + 64 * c) * 4;
      if (q.x > tau) yrow[base + 0] = q.x - tau;
      if (q.y > tau) yrow[base + 1] = q.y - tau;
      if (q.z > tau) yrow[base + 2] = q.z - tau;
      if (q.w > tau) yrow[base + 3] = q.w - tau;
    }
  }
}

extern "C" void kernel_launch(void* const* d_in, const int* in_sizes, int n_in,
                              void* d_out, int out_size, void* d_ws, size_t ws_size,
                              hipStream_t stream) {
  const float* in = (const float*)d_in[0];
  float* out = (float*)d_out;
  const int rows = in_sizes[0] / D;        // 16384
  const int blocks = (rows + 3) / 4;       // 1 row per wave, 4 waves/block
  // Zero the output with a pure-write fill (measured 6.5 TB/s on this
  // harness), then the kernel only reads input + scatters ~14 floats/row.
  hipMemsetAsync(d_out, 0, (size_t)out_size, stream);
  sparsemax_kernel<<<blocks, BLOCK, 0, stream>>>(in, out, rows);
}